// Round 1
// baseline (4298.939 us; speedup 1.0000x reference)
//
#include <hip/hip_runtime.h>

// Swin-style windowed cross-attention, fused, fp32 (correctness-first round).
// One block (256 threads) per window. All intermediates LDS-resident.
//
// Shapes: B_=16384 windows, N=49 tokens, DIM=96, HEADS=3, HD=32, NW=1024.
// q comes from rescaler (W rows 0..95), k/v from rescaled (W rows 96..287).

#define NTOK 49
#define DIMC 96
#define HD   32
#define XS   100   // row stride for x/q/k/v/xo tiles: %4==0 (float4 align), %32==4 (<=4-way banks)
#define WSTR 112   // W tile row stride: %4==0, %32==16 (2-way banks on per-lane-row reads = free)
#define SP   52    // score row stride: %4==0
#define SCALE 0.17677669529663687f  // 32^-0.5

// out[n0+j][ci+32*i] partial: dot over 96 of sX row with sW row (both LDS).
__device__ __forceinline__ void gemm_tile(const float* __restrict__ sX,
                                          const float* __restrict__ sWb,
                                          int ci, int n0, float acc[7][3])
{
#pragma unroll
    for (int j = 0; j < 7; j++) { acc[j][0] = 0.f; acc[j][1] = 0.f; acc[j][2] = 0.f; }
#pragma unroll 4
    for (int kq = 0; kq < 24; kq++) {
        const int kk = kq * 4;
        const float4 w0 = *(const float4*)(sWb + (ci     ) * WSTR + kk);
        const float4 w1 = *(const float4*)(sWb + (ci + 32) * WSTR + kk);
        const float4 w2 = *(const float4*)(sWb + (ci + 64) * WSTR + kk);
#pragma unroll
        for (int j = 0; j < 7; j++) {
            const float4 x4 = *(const float4*)(sX + (n0 + j) * XS + kk);
            acc[j][0] += x4.x * w0.x + x4.y * w0.y + x4.z * w0.z + x4.w * w0.w;
            acc[j][1] += x4.x * w1.x + x4.y * w1.y + x4.z * w1.z + x4.w * w1.w;
            acc[j][2] += x4.x * w2.x + x4.y * w2.y + x4.z * w2.z + x4.w * w2.w;
        }
    }
}

__global__ __launch_bounds__(256)
void swin_xattn_f32(const float* __restrict__ rescaled,
                    const float* __restrict__ rescaler,
                    const float* __restrict__ mask,
                    const float* __restrict__ Wqkv_d,
                    const float* __restrict__ bqkv_d,
                    const float* __restrict__ Wqkv_r,
                    const float* __restrict__ bqkv_r,
                    const float* __restrict__ bias_table,
                    const float* __restrict__ Wproj,
                    const float* __restrict__ bproj,
                    const int* __restrict__ rel_index,
                    float* __restrict__ out,
                    int nW)
{
    // LDS map (floats): [0,4900) xd | [4900,9800) xr | scores reuse [0,7644)
    //                   [9800,20552) W tile | [20552,25452) q->xo | [25452,30352) k | [30352,35252) v
    __shared__ __align__(16) float lds[35252];
    float* sXd = lds;
    float* sXr = lds + 4900;
    float* sS  = lds;            // 147 rows * SP(52) = 7644 <= 9800, valid after k,v done
    float* sW  = lds + 9800;     // 96 * 112
    float* sQ  = lds + 20552;    // later reused as attention output xo
    float* sK  = lds + 25452;
    float* sV  = lds + 30352;

    const int b  = blockIdx.x;
    const int t  = threadIdx.x;
    const int ci = t & 31;
    const int gi = t >> 5;        // 0..7 ; gi==7 idles in GEMM phases (7*7=49 rows)
    const int n0 = gi * 7;

    // ---- stage x_d, x_r and Wq (rescaler rows 0..95) ----
    {
        const float4* gxd = (const float4*)(rescaled + (size_t)b * (NTOK * DIMC));
        const float4* gxr = (const float4*)(rescaler + (size_t)b * (NTOK * DIMC));
        for (int i = t; i < NTOK * DIMC / 4; i += 256) {
            const int e = i * 4; const int n = e / 96, c = e - n * 96;
            *(float4*)(sXd + n * XS + c) = gxd[i];
            *(float4*)(sXr + n * XS + c) = gxr[i];
        }
        const float4* gw = (const float4*)(Wqkv_r);
        for (int i = t; i < 2304; i += 256) {
            const int e = i * 4; const int r = e / 96, c = e - r * 96;
            *(float4*)(sW + r * WSTR + c) = gw[i];
        }
    }
    __syncthreads();

    float acc[7][3];

    // ---- q = (x_r @ Wq^T + bq) * SCALE ----
    if (gi < 7) {
        gemm_tile(sXr, sW, ci, n0, acc);
#pragma unroll
        for (int i = 0; i < 3; i++) {
            const int c = ci + 32 * i;
            const float bb = bqkv_r[c];
#pragma unroll
            for (int j = 0; j < 7; j++) sQ[(n0 + j) * XS + c] = (acc[j][i] + bb) * SCALE;
        }
    }
    __syncthreads();

    // ---- stage Wk (rescaled rows 96..191) ----
    {
        const float4* gw = (const float4*)(Wqkv_d + 96 * 96);
        for (int i = t; i < 2304; i += 256) {
            const int e = i * 4; const int r = e / 96, c = e - r * 96;
            *(float4*)(sW + r * WSTR + c) = gw[i];
        }
    }
    __syncthreads();

    // ---- k = x_d @ Wk^T + bk ----
    if (gi < 7) {
        gemm_tile(sXd, sW, ci, n0, acc);
#pragma unroll
        for (int i = 0; i < 3; i++) {
            const int c = ci + 32 * i;
            const float bb = bqkv_d[96 + c];
#pragma unroll
            for (int j = 0; j < 7; j++) sK[(n0 + j) * XS + c] = acc[j][i] + bb;
        }
    }
    __syncthreads();

    // ---- stage Wv (rescaled rows 192..287) ----
    {
        const float4* gw = (const float4*)(Wqkv_d + 2 * 96 * 96);
        for (int i = t; i < 2304; i += 256) {
            const int e = i * 4; const int r = e / 96, c = e - r * 96;
            *(float4*)(sW + r * WSTR + c) = gw[i];
        }
    }
    __syncthreads();

    // ---- v = x_d @ Wv^T + bv ----
    if (gi < 7) {
        gemm_tile(sXd, sW, ci, n0, acc);
#pragma unroll
        for (int i = 0; i < 3; i++) {
            const int c = ci + 32 * i;
            const float bb = bqkv_d[192 + c];
#pragma unroll
            for (int j = 0; j < 7; j++) sV[(n0 + j) * XS + c] = acc[j][i] + bb;
        }
    }
    __syncthreads();   // x tiles dead from here; sS may overwrite them

    // ---- scores S[h][n][m] = q_h[n] . k_h[m] + bias + mask ----
    {
        const float* maskw = mask + (size_t)(b % nW) * (NTOK * NTOK);
        for (int o = t; o < 3 * NTOK * NTOK; o += 256) {
            const int h = o / 2401; const int r = o - h * 2401;
            const int n = r / 49;   const int m = r - n * 49;
            const float* qp = sQ + n * XS + h * HD;
            const float* kp = sK + m * XS + h * HD;
            float a = 0.f;
#pragma unroll
            for (int kk = 0; kk < HD; kk += 4) {
                const float4 q4 = *(const float4*)(qp + kk);
                const float4 k4 = *(const float4*)(kp + kk);
                a += q4.x * k4.x + q4.y * k4.y + q4.z * k4.z + q4.w * k4.w;
            }
            a += bias_table[rel_index[r] * 3 + h] + maskw[r];
            sS[(h * 49 + n) * SP + m] = a;
        }
    }
    __syncthreads();

    // ---- softmax over m (one thread per (h,n) row) ----
    if (t < 147) {
        float* row = sS + t * SP;
        float mx = row[0];
        for (int m = 1; m < 49; m++) mx = fmaxf(mx, row[m]);
        float s = 0.f;
        for (int m = 0; m < 49; m++) { const float e = __expf(row[m] - mx); row[m] = e; s += e; }
        const float inv = 1.0f / s;
        for (int m = 0; m < 49; m++) row[m] *= inv;
    }
    __syncthreads();

    // ---- xo[n][h*32+d] = sum_m P[h][n][m] * v[m][h*32+d]  (xo overwrites q) ----
    for (int o = t; o < NTOK * DIMC; o += 256) {
        const int r = o >> 5, d = o & 31;
        const int h = r / 49, n = r - h * 49;
        const float* pp = sS + r * SP;
        const float* vp = sV + h * HD + d;
        float a = 0.f;
#pragma unroll 7
        for (int m = 0; m < 49; m++) a += pp[m] * vp[m * XS];
        sQ[n * XS + h * HD + d] = a;
    }
    // stage Wproj (sW free since v-phase) in the same phase
    {
        const float4* gw = (const float4*)(Wproj);
        for (int i = t; i < 2304; i += 256) {
            const int e = i * 4; const int r = e / 96, c = e - r * 96;
            *(float4*)(sW + r * WSTR + c) = gw[i];
        }
    }
    __syncthreads();

    // ---- out = xo @ Wproj^T + bproj ----
    if (gi < 7) {
        gemm_tile(sQ, sW, ci, n0, acc);
        float* op = out + (size_t)b * (NTOK * DIMC);
#pragma unroll
        for (int i = 0; i < 3; i++) {
            const int c = ci + 32 * i;
            const float bb = bproj[c];
#pragma unroll
            for (int j = 0; j < 7; j++) op[(n0 + j) * 96 + c] = acc[j][i] + bb;
        }
    }
}

extern "C" void kernel_launch(void* const* d_in, const int* in_sizes, int n_in,
                              void* d_out, int out_size, void* d_ws, size_t ws_size,
                              hipStream_t stream)
{
    const float* rescaled = (const float*)d_in[0];
    const float* rescaler = (const float*)d_in[1];
    const float* mask     = (const float*)d_in[2];
    const float* Wqkv_d   = (const float*)d_in[3];
    const float* bqkv_d   = (const float*)d_in[4];
    const float* Wqkv_r   = (const float*)d_in[5];
    const float* bqkv_r   = (const float*)d_in[6];
    const float* bias_t   = (const float*)d_in[7];
    const float* Wproj    = (const float*)d_in[8];
    const float* bproj    = (const float*)d_in[9];
    const int*   rel      = (const int*)d_in[10];
    float* out = (float*)d_out;

    const int B  = in_sizes[0] / (NTOK * DIMC);   // 16384
    const int nW = in_sizes[2] / (NTOK * NTOK);   // 1024

    hipLaunchKernelGGL(swin_xattn_f32, dim3(B), dim3(256), 0, stream,
                       rescaled, rescaler, mask, Wqkv_d, bqkv_d, Wqkv_r, bqkv_r,
                       bias_t, Wproj, bproj, rel, out, nW);
}